// Round 4
// baseline (1651.628 us; speedup 1.0000x reference)
//
#include <hip/hip_runtime.h>
#include <math.h>

#define BB 4096
#define DD 2048
#define CC 10000
#define KK 10
#define NT 256
#define NW 4
#define NF4 2500  // CC / 4
#define TRI(k) ((k)*((k)+1)/2)
#define CH 256            // D-chunk in floats (64 lanes x float4)
#define NCH (DD / CH)     // 8 chunks

// Gram pair tables: accumulator t in [0,55) is pair (PJ[t], PK[t]), j<=k.
constexpr int PJ[55] = {0, 0,1, 0,1,2, 0,1,2,3, 0,1,2,3,4, 0,1,2,3,4,5,
                        0,1,2,3,4,5,6, 0,1,2,3,4,5,6,7, 0,1,2,3,4,5,6,7,8,
                        0,1,2,3,4,5,6,7,8,9};
constexpr int PK[55] = {0, 1,1, 2,2,2, 3,3,3,3, 4,4,4,4,4, 5,5,5,5,5,5,
                        6,6,6,6,6,6,6, 7,7,7,7,7,7,7,7, 8,8,8,8,8,8,8,8,8,
                        9,9,9,9,9,9,9,9,9,9};

// async global->LDS, 16B per lane; LDS dest = uniform base + lane*16 (linear)
typedef __attribute__((address_space(3))) void       lds_void;
typedef const __attribute__((address_space(1))) void gbl_cvoid;
__device__ __forceinline__ void gll16(const float* gp, float* lp) {
    __builtin_amdgcn_global_load_lds((gbl_cvoid*)gp, (lds_void*)lp, 16, 0, 0);
}

// ---------------- Kernel 1: top-10 SET per row (unchanged, known-good) -------
__global__ __launch_bounds__(NT, 6) void topk_kernel(
    const float* __restrict__ logits, const int* __restrict__ y,
    int* __restrict__ topk)
{
    __shared__ float s_cv[NW * KK];
    __shared__ int   s_ci[NW * KK];

    const int b = blockIdx.x, tid = threadIdx.x;
    const int lane = tid & 63, wave = tid >> 6;
    const int yb = y[b];

    float4 lg[10];
    const float4* lrow = (const float4*)(logits + (size_t)b * CC);
    #pragma unroll
    for (int j = 0; j < 10; ++j) {
        const int i4 = tid + 256 * j;
        if (i4 < NF4) lg[j] = lrow[i4];
        else          lg[j] = make_float4(-3e38f, -3e38f, -3e38f, -3e38f);
    }
    #pragma unroll
    for (int j = 0; j < 10; ++j) {        // mask true class
        const int rel = yb - 4 * (tid + 256 * j);
        if (rel == 0) lg[j].x = -3e38f;
        else if (rel == 1) lg[j].y = -3e38f;
        else if (rel == 2) lg[j].z = -3e38f;
        else if (rel == 3) lg[j].w = -3e38f;
    }

    float lbest; int lbidx;
    auto rescan = [&]() {
        lbest = -3.1e38f; lbidx = 0x7fffffff;
        #pragma unroll
        for (int j = 0; j < 10; ++j) {
            const int base = 4 * (tid + 256 * j);
            if (lg[j].x > lbest) { lbest = lg[j].x; lbidx = base + 0; }
            if (lg[j].y > lbest) { lbest = lg[j].y; lbidx = base + 1; }
            if (lg[j].z > lbest) { lbest = lg[j].z; lbidx = base + 2; }
            if (lg[j].w > lbest) { lbest = lg[j].w; lbidx = base + 3; }
        }
    };
    rescan();

    for (int r = 0; r < KK; ++r) {        // 10 wave-local rounds, no barriers
        float bv = lbest; int bi = lbidx;
        #pragma unroll
        for (int off = 32; off > 0; off >>= 1) {
            const float ov = __shfl_down(bv, off, 64);
            const int   oi = __shfl_down(bi, off, 64);
            if (ov > bv || (ov == bv && oi < bi)) { bv = ov; bi = oi; }
        }
        bv = __shfl(bv, 0, 64);
        bi = __shfl(bi, 0, 64);
        if (lane == 0) { s_cv[wave * KK + r] = bv; s_ci[wave * KK + r] = bi; }
        if (lbidx == bi) {
            const int jw = ((bi >> 2) - tid) >> 8;
            const int cw = bi & 3;
            #pragma unroll
            for (int j = 0; j < 10; ++j) if (j == jw) {
                if (cw == 0) lg[j].x = -3e38f;
                else if (cw == 1) lg[j].y = -3e38f;
                else if (cw == 2) lg[j].z = -3e38f;
                else lg[j].w = -3e38f;
            }
            rescan();
        }
    }
    __syncthreads();

    if (wave == 0) {                       // top-10 of the 40 wave candidates
        float cv = (lane < NW * KK) ? s_cv[lane] : -3.1e38f;
        int   ci = (lane < NW * KK) ? s_ci[lane] : 0x7fffffff;
        for (int r = 0; r < KK; ++r) {
            float bv = cv; int bi = ci;
            #pragma unroll
            for (int off = 32; off > 0; off >>= 1) {
                const float ov = __shfl_down(bv, off, 64);
                const int   oi = __shfl_down(bi, off, 64);
                if (ov > bv || (ov == bv && oi < bi)) { bv = ov; bi = oi; }
            }
            bi = __shfl(bi, 0, 64);
            if (lane == 0) topk[b * KK + r] = bi;
            if (ci == bi) cv = -3.1e38f;
        }
    }
}

// ---------------- Pass-1: LDS-staged chunks + wave-owned accumulator slice ---
// Per chunk: the block cooperatively DMAs the 11 gathered rows (wy + 10 wk)
// into LDS (each row-chunk = one global_load_lds_dwordx4 wave-op), then each
// wave accumulates its CNT of the 75 outputs from LDS. Block W-traffic drops
// from 35 row-reads to 11 (exactly-once); redundancy moves to LDS (~free).
// Lane element mapping identical to round 2 -> bit-identical numerics.
template<int LO, int CNT, int NROW, bool WZN>
__device__ __forceinline__ void pass1(
    const float* __restrict__ W, const float* __restrict__ z,
    const float* __restrict__ noise, size_t zoff,
    size_t rb0, size_t rb1, size_t rb2, int has2,
    float* lp0, float* lp1, float* lp2,
    int lane, float* s_w, float* s_g)
{
    float acc[CNT];
    #pragma unroll
    for (int t = 0; t < CNT; ++t) acc[t] = 0.0f;

    for (int c = 0; c < NCH; ++c) {
        const int col = (c << 8) + (lane << 2);      // floats
        gll16(W + rb0 + col, lp0);
        gll16(W + rb1 + col, lp1);
        if (has2) gll16(W + rb2 + col, lp2);
        __syncthreads();                              // drains vmcnt -> LDS valid

        const float4* sw4 = (const float4*)s_w;
        const float4 wy4 = sw4[(10 << 6) + lane];
        float4 a4[NROW];
        #pragma unroll
        for (int k = 0; k < NROW; ++k) {
            const float4 wk4 = sw4[(k << 6) + lane];
            a4[k].x = wy4.x - wk4.x; a4[k].y = wy4.y - wk4.y;
            a4[k].z = wy4.z - wk4.z; a4[k].w = wy4.w - wk4.w;
        }
        float4 z4 = make_float4(0.f, 0.f, 0.f, 0.f), n4 = z4;
        if (WZN) {
            z4 = ((const float4*)(z + zoff))[(c << 6) + lane];
            n4 = ((const float4*)(noise + zoff))[(c << 6) + lane];
        }
        #pragma unroll
        for (int e = 0; e < 4; ++e) {
            float ak[NROW];
            #pragma unroll
            for (int k = 0; k < NROW; ++k)
                ak[k] = (e == 0) ? a4[k].x : (e == 1) ? a4[k].y
                      : (e == 2) ? a4[k].z : a4[k].w;
            const float ze = (e == 0) ? z4.x : (e == 1) ? z4.y : (e == 2) ? z4.z : z4.w;
            const float ne = (e == 0) ? n4.x : (e == 1) ? n4.y : (e == 2) ? n4.z : n4.w;
            #pragma unroll
            for (int t = 0; t < CNT; ++t) {
                const int g = LO + t;                 // compile-time constant
                if (g < 55)      acc[t] += ak[PJ[g < 55 ? g : 0]] * ak[PK[g < 55 ? g : 0]];
                else if (g < 65) acc[t] += ak[(g - 55) < NROW ? (g - 55) : 0] * ze;
                else             acc[t] += ak[(g - 65) < NROW ? (g - 65) : 0] * ne;
            }
        }
        __syncthreads();                              // all reads done before next stage
    }
    // wave covered all of D -> shuffle reduce is the FULL sum
    #pragma unroll
    for (int t = 0; t < CNT; ++t) {
        float x = acc[t];
        #pragma unroll
        for (int off = 32; off > 0; off >>= 1) x += __shfl_down(x, off, 64);
        if (lane == 0) s_g[LO + t] = x;
    }
}

// ---------------- Kernel 2: Gram/Cholesky augmentation -----------------------
__global__ __launch_bounds__(NT, 5) void aug_kernel(
    const float* __restrict__ z, const int* __restrict__ y,
    const float* __restrict__ W, const float* __restrict__ noise,
    const int* __restrict__ topk, float* __restrict__ out, int write_tail)
{
    __shared__ __align__(16) float s_w[11 * CH];   // 11 row-chunk slots (11.0 KB)
    __shared__ float s_g[80];          // 75 used: Gram(55), m(10), v(10)
    __shared__ float s_sol[16];        // cvec[10], scale, valid

    const int b = blockIdx.x, tid = threadIdx.x;
    const int lane = tid & 63, wave = tid >> 6;
    const int yb = y[b];

    int kidx[KK];
    #pragma unroll
    for (int k = 0; k < KK; ++k) kidx[k] = topk[b * KK + k];

    const size_t zoff = (size_t)b * DD;
    const size_t wyo  = (size_t)yb * DD;

    // stage rows for this wave: slots {wave, wave+4, wave+8} (slot 10 == wy)
    const size_t rb0 = (size_t)topk[b * KK + wave] * DD;
    const size_t rb1 = (size_t)topk[b * KK + wave + 4] * DD;
    const size_t rb2 = (wave == 2) ? wyo
                     : (wave < 2) ? (size_t)topk[b * KK + wave + 8] * DD : 0;
    const int has2 = (wave < 3) ? 1 : 0;
    float* lp0 = s_w + wave * CH;
    float* lp1 = s_w + (wave + 4) * CH;
    float* lp2 = s_w + (wave + 8) * CH;   // only used when has2

    if (wave == 0)      pass1< 0, 19,  6, false>(W, z, noise, zoff, rb0, rb1, rb2, has2, lp0, lp1, lp2, lane, s_w, s_g);
    else if (wave == 1) pass1<19, 19,  9, false>(W, z, noise, zoff, rb0, rb1, rb2, has2, lp0, lp1, lp2, lane, s_w, s_g);
    else if (wave == 2) pass1<38, 17, 10, false>(W, z, noise, zoff, rb0, rb1, rb2, has2, lp0, lp1, lp2, lane, s_w, s_g);
    else                pass1<55, 20, 10, true >(W, z, noise, zoff, rb0, rb1, rb2, has2, lp0, lp1, lp2, lane, s_w, s_g);
    __syncthreads();

    if (wave == 0) {   // Cholesky + triangular solves, redundant across wave 0
        float g[75];
        #pragma unroll
        for (int t = 0; t < 75; ++t) g[t] = s_g[t];

        float dinv[KK];
        unsigned keepmask = 0u;
        #pragma unroll
        for (int k = 0; k < KK; ++k) {
            float s = g[TRI(k) + k];
            #pragma unroll
            for (int j = 0; j < KK; ++j) if (j < k) { const float l = g[TRI(k) + j]; s -= l * l; }
            const float dkk = sqrtf(fmaxf(s, 0.0f));
            const bool kp = dkk > 1e-6f;
            if (kp) keepmask |= (1u << k);
            dinv[k] = kp ? 1.0f / dkk : 0.0f;
            g[TRI(k) + k] = dkk;
            #pragma unroll
            for (int i = 0; i < KK; ++i) if (i > k) {
                float t2 = g[TRI(i) + k];
                #pragma unroll
                for (int j = 0; j < KK; ++j) if (j < k) t2 -= g[TRI(i) + j] * g[TRI(k) + j];
                g[TRI(i) + k] = t2 * dinv[k];
            }
        }
        float cvec[KK];
        #pragma unroll
        for (int i = 0; i < KK; ++i) {
            float s = g[65 + i];
            #pragma unroll
            for (int j = 0; j < KK; ++j) if (j < i) s -= g[TRI(i) + j] * cvec[j];
            cvec[i] = s * dinv[i];
        }
        #pragma unroll
        for (int i = KK - 1; i >= 0; --i) {
            float s = cvec[i];
            #pragma unroll
            for (int j = 0; j < KK; ++j) if (j > i) s -= g[TRI(j) + i] * cvec[j];
            cvec[i] = s * dinv[i];
        }
        const float denomf = 6.9914645e-8f;   // 2*EPS*log(20) + EPS (fp32)
        float amin = 3.0e38f;
        #pragma unroll
        for (int k = 0; k < KK; ++k) {
            const float sl = fmaxf(g[55 + k], 0.0f);   // GAMMA = 0
            amin = fminf(amin, sl * sl / denomf);
        }
        const bool valid = (keepmask != 0u) && (amin > 0.0f) && isfinite(amin);
        const float scale = valid ? sqrtf(amin) : 0.0f;
        if (lane == 0) {
            #pragma unroll
            for (int k = 0; k < KK; ++k) s_sol[k] = cvec[k];
            s_sol[10] = scale;
            s_sol[11] = valid ? 1.0f : 0.0f;
        }
    }
    __syncthreads();

    float cvec[KK];
    #pragma unroll
    for (int k = 0; k < KK; ++k) cvec[k] = s_sol[k];
    const float scale = s_sol[10];

    // pass 2: re-gather W chunks (L2/L3-hot), project, write out
    #pragma unroll
    for (int c = 0; c < 2; ++c) {
        const size_t coff = (size_t)c * 1024;
        const float4 wy4 = ((const float4*)(W + wyo + coff))[tid];
        float4 proj = make_float4(0.f, 0.f, 0.f, 0.f);
        float csum = 0.f;
        #pragma unroll
        for (int k = 0; k < KK; ++k) {
            const float4 wk4 = ((const float4*)(W + (size_t)kidx[k] * DD + coff))[tid];
            proj.x -= cvec[k] * wk4.x; proj.y -= cvec[k] * wk4.y;
            proj.z -= cvec[k] * wk4.z; proj.w -= cvec[k] * wk4.w;
            csum += cvec[k];
        }
        proj.x += csum * wy4.x; proj.y += csum * wy4.y;
        proj.z += csum * wy4.z; proj.w += csum * wy4.w;
        const float4 zc = ((const float4*)(z + zoff + coff))[tid];
        const float4 nc = ((const float4*)(noise + zoff + coff))[tid];
        float4 o;
        o.x = zc.x + scale * (nc.x - proj.x);
        o.y = zc.y + scale * (nc.y - proj.y);
        o.z = zc.z + scale * (nc.z - proj.z);
        o.w = zc.w + scale * (nc.w - proj.w);
        ((float4*)(out + zoff + coff))[tid] = o;
    }

    if (write_tail && tid == 0) {
        out[(size_t)BB * DD + b] = (float)yb;
        out[(size_t)BB * DD + BB + b] = s_sol[11];
    }
}

extern "C" void kernel_launch(void* const* d_in, const int* in_sizes, int n_in,
                              void* d_out, int out_size, void* d_ws, size_t ws_size,
                              hipStream_t stream) {
    const float* z      = (const float*)d_in[0];
    const int*   y      = (const int*)d_in[1];
    const float* logits = (const float*)d_in[2];
    const float* W      = (const float*)d_in[3];
    const float* noise  = (const float*)d_in[4];
    float* out = (float*)d_out;
    int* topk = (int*)d_ws;   // BB*KK ints

    topk_kernel<<<BB, NT, 0, stream>>>(logits, y, topk);
    const int write_tail = (out_size >= BB * DD + 2 * BB) ? 1 : 0;
    aug_kernel<<<BB, NT, 0, stream>>>(z, y, W, noise, topk, out, write_tail);
}

// Round 5
// 459.412 us; speedup vs baseline: 3.5951x; 3.5951x over previous
//
#include <hip/hip_runtime.h>
#include <math.h>

#define BB 4096
#define DD 2048
#define CC 10000
#define KK 10
#define NT 256
#define NW 4
#define NF4 2500  // CC / 4
#define TRI(k) ((k)*((k)+1)/2)
#define CH 256            // D-chunk in floats (64 lanes x float4)
#define NCH (DD / CH)     // 8 chunks

// Gram pair tables: accumulator t in [0,55) is pair (PJ[t], PK[t]), j<=k.
constexpr int PJ[55] = {0, 0,1, 0,1,2, 0,1,2,3, 0,1,2,3,4, 0,1,2,3,4,5,
                        0,1,2,3,4,5,6, 0,1,2,3,4,5,6,7, 0,1,2,3,4,5,6,7,8,
                        0,1,2,3,4,5,6,7,8,9};
constexpr int PK[55] = {0, 1,1, 2,2,2, 3,3,3,3, 4,4,4,4,4, 5,5,5,5,5,5,
                        6,6,6,6,6,6,6, 7,7,7,7,7,7,7,7, 8,8,8,8,8,8,8,8,8,
                        9,9,9,9,9,9,9,9,9,9};

// async global->LDS, 16B per lane; LDS dest = uniform base + lane*16 (linear)
typedef __attribute__((address_space(3))) void       lds_void;
typedef const __attribute__((address_space(1))) void gbl_cvoid;
__device__ __forceinline__ void gll16(const float* gp, float* lp) {
    __builtin_amdgcn_global_load_lds((gbl_cvoid*)gp, (lds_void*)lp, 16, 0, 0);
}

// ---------------- Kernel 1: top-10 SET per row (unchanged, known-good) -------
__global__ __launch_bounds__(NT, 6) void topk_kernel(
    const float* __restrict__ logits, const int* __restrict__ y,
    int* __restrict__ topk)
{
    __shared__ float s_cv[NW * KK];
    __shared__ int   s_ci[NW * KK];

    const int b = blockIdx.x, tid = threadIdx.x;
    const int lane = tid & 63, wave = tid >> 6;
    const int yb = y[b];

    float4 lg[10];
    const float4* lrow = (const float4*)(logits + (size_t)b * CC);
    #pragma unroll
    for (int j = 0; j < 10; ++j) {
        const int i4 = tid + 256 * j;
        if (i4 < NF4) lg[j] = lrow[i4];
        else          lg[j] = make_float4(-3e38f, -3e38f, -3e38f, -3e38f);
    }
    #pragma unroll
    for (int j = 0; j < 10; ++j) {        // mask true class
        const int rel = yb - 4 * (tid + 256 * j);
        if (rel == 0) lg[j].x = -3e38f;
        else if (rel == 1) lg[j].y = -3e38f;
        else if (rel == 2) lg[j].z = -3e38f;
        else if (rel == 3) lg[j].w = -3e38f;
    }

    float lbest; int lbidx;
    auto rescan = [&]() {
        lbest = -3.1e38f; lbidx = 0x7fffffff;
        #pragma unroll
        for (int j = 0; j < 10; ++j) {
            const int base = 4 * (tid + 256 * j);
            if (lg[j].x > lbest) { lbest = lg[j].x; lbidx = base + 0; }
            if (lg[j].y > lbest) { lbest = lg[j].y; lbidx = base + 1; }
            if (lg[j].z > lbest) { lbest = lg[j].z; lbidx = base + 2; }
            if (lg[j].w > lbest) { lbest = lg[j].w; lbidx = base + 3; }
        }
    };
    rescan();

    for (int r = 0; r < KK; ++r) {        // 10 wave-local rounds, no barriers
        float bv = lbest; int bi = lbidx;
        #pragma unroll
        for (int off = 32; off > 0; off >>= 1) {
            const float ov = __shfl_down(bv, off, 64);
            const int   oi = __shfl_down(bi, off, 64);
            if (ov > bv || (ov == bv && oi < bi)) { bv = ov; bi = oi; }
        }
        bv = __shfl(bv, 0, 64);
        bi = __shfl(bi, 0, 64);
        if (lane == 0) { s_cv[wave * KK + r] = bv; s_ci[wave * KK + r] = bi; }
        if (lbidx == bi) {
            const int jw = ((bi >> 2) - tid) >> 8;
            const int cw = bi & 3;
            #pragma unroll
            for (int j = 0; j < 10; ++j) if (j == jw) {
                if (cw == 0) lg[j].x = -3e38f;
                else if (cw == 1) lg[j].y = -3e38f;
                else if (cw == 2) lg[j].z = -3e38f;
                else lg[j].w = -3e38f;
            }
            rescan();
        }
    }
    __syncthreads();

    if (wave == 0) {                       // top-10 of the 40 wave candidates
        float cv = (lane < NW * KK) ? s_cv[lane] : -3.1e38f;
        int   ci = (lane < NW * KK) ? s_ci[lane] : 0x7fffffff;
        for (int r = 0; r < KK; ++r) {
            float bv = cv; int bi = ci;
            #pragma unroll
            for (int off = 32; off > 0; off >>= 1) {
                const float ov = __shfl_down(bv, off, 64);
                const int   oi = __shfl_down(bi, off, 64);
                if (ov > bv || (ov == bv && oi < bi)) { bv = ov; bi = oi; }
            }
            bi = __shfl(bi, 0, 64);
            if (lane == 0) topk[b * KK + r] = bi;
            if (ci == bi) cv = -3.1e38f;
        }
    }
}

// ---------------- Pass-1: LDS-staged chunks + wave-owned accumulator slice ---
// Identical structure to the spill-free round-2 pass1_accum (same acc/a4
// register footprint, same `#pragma unroll 1` D-loop, same lane->element map
// -> bit-identical numerics); only the a4 SOURCE changed: cooperative
// global_load_lds staging (11 exactly-once row reads/block) + LDS reads.
template<int LO, int CNT, int NROW, bool WZN>
__device__ __forceinline__ void pass1(
    const float* __restrict__ W, const float* __restrict__ z,
    const float* __restrict__ noise, size_t zoff,
    size_t rb0, size_t rb1, size_t rb2, int has2,
    float* lp0, float* lp1, float* lp2,
    int lane, float* s_w, float* s_g)
{
    float acc[CNT];
    #pragma unroll
    for (int t = 0; t < CNT; ++t) acc[t] = 0.0f;

    #pragma unroll 1   // CRITICAL: unrolling this loop multiplies a4/addr live
    for (int c = 0; c < NCH; ++c) {   //   ranges -> scratch demotion (round 4)
        const int col = (c << 8) + (lane << 2);      // floats
        gll16(W + rb0 + col, lp0);
        gll16(W + rb1 + col, lp1);
        if (has2) gll16(W + rb2 + col, lp2);
        __syncthreads();                              // drains vmcnt -> LDS valid

        const float4* sw4 = (const float4*)s_w;
        const float4 wy4 = sw4[(10 << 6) + lane];
        float4 a4[NROW];
        #pragma unroll
        for (int k = 0; k < NROW; ++k) {
            const float4 wk4 = sw4[(k << 6) + lane];
            a4[k].x = wy4.x - wk4.x; a4[k].y = wy4.y - wk4.y;
            a4[k].z = wy4.z - wk4.z; a4[k].w = wy4.w - wk4.w;
        }
        float4 z4 = make_float4(0.f, 0.f, 0.f, 0.f), n4 = z4;
        if (WZN) {
            z4 = ((const float4*)(z + zoff))[(c << 6) + lane];
            n4 = ((const float4*)(noise + zoff))[(c << 6) + lane];
        }
        #pragma unroll
        for (int e = 0; e < 4; ++e) {
            float ak[NROW];
            #pragma unroll
            for (int k = 0; k < NROW; ++k)
                ak[k] = (e == 0) ? a4[k].x : (e == 1) ? a4[k].y
                      : (e == 2) ? a4[k].z : a4[k].w;
            const float ze = (e == 0) ? z4.x : (e == 1) ? z4.y : (e == 2) ? z4.z : z4.w;
            const float ne = (e == 0) ? n4.x : (e == 1) ? n4.y : (e == 2) ? n4.z : n4.w;
            #pragma unroll
            for (int t = 0; t < CNT; ++t) {
                const int g = LO + t;                 // compile-time constant
                if (g < 55)      acc[t] += ak[PJ[g < 55 ? g : 0]] * ak[PK[g < 55 ? g : 0]];
                else if (g < 65) acc[t] += ak[(g - 55) < NROW ? (g - 55) : 0] * ze;
                else             acc[t] += ak[(g - 65) < NROW ? (g - 65) : 0] * ne;
            }
        }
        __syncthreads();                              // all reads done before next stage
    }
    // wave covered all of D -> shuffle reduce is the FULL sum
    #pragma unroll
    for (int t = 0; t < CNT; ++t) {
        float x = acc[t];
        #pragma unroll
        for (int off = 32; off > 0; off >>= 1) x += __shfl_down(x, off, 64);
        if (lane == 0) s_g[LO + t] = x;
    }
}

// ---------------- Kernel 2: Gram/Cholesky augmentation -----------------------
// __launch_bounds__(256,4): VGPR cap 128 (the round-2-proven budget for this
// acc/a4 structure, 64 VGPR actual). (256,5)'s ~96 cap contributed to the
// round-4 scratch demotion.
__global__ __launch_bounds__(NT, 4) void aug_kernel(
    const float* __restrict__ z, const int* __restrict__ y,
    const float* __restrict__ W, const float* __restrict__ noise,
    const int* __restrict__ topk, float* __restrict__ out, int write_tail)
{
    __shared__ __align__(16) float s_w[11 * CH];   // 11 row-chunk slots (11.0 KB)
    __shared__ float s_g[80];          // 75 used: Gram(55), m(10), v(10)
    __shared__ float s_sol[16];        // cvec[10], scale, valid

    const int b = blockIdx.x, tid = threadIdx.x;
    const int lane = tid & 63, wave = tid >> 6;
    const int yb = y[b];

    int kidx[KK];
    #pragma unroll
    for (int k = 0; k < KK; ++k) kidx[k] = topk[b * KK + k];

    const size_t zoff = (size_t)b * DD;
    const size_t wyo  = (size_t)yb * DD;

    // stage rows for this wave: slots {wave, wave+4, wave+8} (slot 10 == wy)
    const size_t rb0 = (size_t)kidx[wave] * DD;
    const size_t rb1 = (size_t)kidx[wave + 4] * DD;
    const size_t rb2 = (wave == 2) ? wyo
                     : (wave < 2) ? (size_t)kidx[wave + 8] * DD : 0;
    const int has2 = (wave < 3) ? 1 : 0;
    float* lp0 = s_w + wave * CH;
    float* lp1 = s_w + (wave + 4) * CH;
    float* lp2 = s_w + (wave + 8) * CH;   // only used when has2

    if (wave == 0)      pass1< 0, 19,  6, false>(W, z, noise, zoff, rb0, rb1, rb2, has2, lp0, lp1, lp2, lane, s_w, s_g);
    else if (wave == 1) pass1<19, 19,  9, false>(W, z, noise, zoff, rb0, rb1, rb2, has2, lp0, lp1, lp2, lane, s_w, s_g);
    else if (wave == 2) pass1<38, 17, 10, false>(W, z, noise, zoff, rb0, rb1, rb2, has2, lp0, lp1, lp2, lane, s_w, s_g);
    else                pass1<55, 20, 10, true >(W, z, noise, zoff, rb0, rb1, rb2, has2, lp0, lp1, lp2, lane, s_w, s_g);
    __syncthreads();

    if (wave == 0) {   // Cholesky + triangular solves, redundant across wave 0
        float g[75];
        #pragma unroll
        for (int t = 0; t < 75; ++t) g[t] = s_g[t];

        float dinv[KK];
        unsigned keepmask = 0u;
        #pragma unroll
        for (int k = 0; k < KK; ++k) {
            float s = g[TRI(k) + k];
            #pragma unroll
            for (int j = 0; j < KK; ++j) if (j < k) { const float l = g[TRI(k) + j]; s -= l * l; }
            const float dkk = sqrtf(fmaxf(s, 0.0f));
            const bool kp = dkk > 1e-6f;
            if (kp) keepmask |= (1u << k);
            dinv[k] = kp ? 1.0f / dkk : 0.0f;
            g[TRI(k) + k] = dkk;
            #pragma unroll
            for (int i = 0; i < KK; ++i) if (i > k) {
                float t2 = g[TRI(i) + k];
                #pragma unroll
                for (int j = 0; j < KK; ++j) if (j < k) t2 -= g[TRI(i) + j] * g[TRI(k) + j];
                g[TRI(i) + k] = t2 * dinv[k];
            }
        }
        float cvec[KK];
        #pragma unroll
        for (int i = 0; i < KK; ++i) {
            float s = g[65 + i];
            #pragma unroll
            for (int j = 0; j < KK; ++j) if (j < i) s -= g[TRI(i) + j] * cvec[j];
            cvec[i] = s * dinv[i];
        }
        #pragma unroll
        for (int i = KK - 1; i >= 0; --i) {
            float s = cvec[i];
            #pragma unroll
            for (int j = 0; j < KK; ++j) if (j > i) s -= g[TRI(j) + i] * cvec[j];
            cvec[i] = s * dinv[i];
        }
        const float denomf = 6.9914645e-8f;   // 2*EPS*log(20) + EPS (fp32)
        float amin = 3.0e38f;
        #pragma unroll
        for (int k = 0; k < KK; ++k) {
            const float sl = fmaxf(g[55 + k], 0.0f);   // GAMMA = 0
            amin = fminf(amin, sl * sl / denomf);
        }
        const bool valid = (keepmask != 0u) && (amin > 0.0f) && isfinite(amin);
        const float scale = valid ? sqrtf(amin) : 0.0f;
        if (lane == 0) {
            #pragma unroll
            for (int k = 0; k < KK; ++k) s_sol[k] = cvec[k];
            s_sol[10] = scale;
            s_sol[11] = valid ? 1.0f : 0.0f;
        }
    }
    __syncthreads();

    float cvec[KK];
    #pragma unroll
    for (int k = 0; k < KK; ++k) cvec[k] = s_sol[k];
    const float scale = s_sol[10];

    // pass 2: re-gather W chunks (L2/L3-hot), project, write out
    #pragma unroll
    for (int c = 0; c < 2; ++c) {
        const size_t coff = (size_t)c * 1024;
        const float4 wy4 = ((const float4*)(W + wyo + coff))[tid];
        float4 proj = make_float4(0.f, 0.f, 0.f, 0.f);
        float csum = 0.f;
        #pragma unroll
        for (int k = 0; k < KK; ++k) {
            const float4 wk4 = ((const float4*)(W + (size_t)kidx[k] * DD + coff))[tid];
            proj.x -= cvec[k] * wk4.x; proj.y -= cvec[k] * wk4.y;
            proj.z -= cvec[k] * wk4.z; proj.w -= cvec[k] * wk4.w;
            csum += cvec[k];
        }
        proj.x += csum * wy4.x; proj.y += csum * wy4.y;
        proj.z += csum * wy4.z; proj.w += csum * wy4.w;
        const float4 zc = ((const float4*)(z + zoff + coff))[tid];
        const float4 nc = ((const float4*)(noise + zoff + coff))[tid];
        float4 o;
        o.x = zc.x + scale * (nc.x - proj.x);
        o.y = zc.y + scale * (nc.y - proj.y);
        o.z = zc.z + scale * (nc.z - proj.z);
        o.w = zc.w + scale * (nc.w - proj.w);
        ((float4*)(out + zoff + coff))[tid] = o;
    }

    if (write_tail && tid == 0) {
        out[(size_t)BB * DD + b] = (float)yb;
        out[(size_t)BB * DD + BB + b] = s_sol[11];
    }
}

extern "C" void kernel_launch(void* const* d_in, const int* in_sizes, int n_in,
                              void* d_out, int out_size, void* d_ws, size_t ws_size,
                              hipStream_t stream) {
    const float* z      = (const float*)d_in[0];
    const int*   y      = (const int*)d_in[1];
    const float* logits = (const float*)d_in[2];
    const float* W      = (const float*)d_in[3];
    const float* noise  = (const float*)d_in[4];
    float* out = (float*)d_out;
    int* topk = (int*)d_ws;   // BB*KK ints

    topk_kernel<<<BB, NT, 0, stream>>>(logits, y, topk);
    const int write_tail = (out_size >= BB * DD + 2 * BB) ? 1 : 0;
    aug_kernel<<<BB, NT, 0, stream>>>(z, y, W, noise, topk, out, write_tail);
}

// Round 6
// 439.100 us; speedup vs baseline: 3.7614x; 1.0463x over previous
//
#include <hip/hip_runtime.h>
#include <math.h>

#define BB 4096
#define DD 2048
#define CC 10000
#define KK 10
#define NT 256
#define NW 4
#define NF4 2500  // CC / 4
#define TRI(k) ((k)*((k)+1)/2)

// Gram pair tables: accumulator t in [0,55) is pair (PJ[t], PK[t]), j<=k.
constexpr int PJ[55] = {0, 0,1, 0,1,2, 0,1,2,3, 0,1,2,3,4, 0,1,2,3,4,5,
                        0,1,2,3,4,5,6, 0,1,2,3,4,5,6,7, 0,1,2,3,4,5,6,7,8,
                        0,1,2,3,4,5,6,7,8,9};
constexpr int PK[55] = {0, 1,1, 2,2,2, 3,3,3,3, 4,4,4,4,4, 5,5,5,5,5,5,
                        6,6,6,6,6,6,6, 7,7,7,7,7,7,7,7, 8,8,8,8,8,8,8,8,8,
                        9,9,9,9,9,9,9,9,9,9};

// ---------------- Pass-1: wave-owned accumulator slice (round-2 code, 64 VGPR,
// verified spill-free @150us). Wave scans full D (8 iters x 64 lanes x float4),
// gathers wy + NROW rows per iter (~11 loads in flight), accumulates its CNT
// of the 75 outputs. 4x wave redundancy on row reads is L2-absorbed (measured:
// round-2 FETCH == round-5 staged FETCH). Bit-identical numerics to round 2.
template<int LO, int CNT, int NROW, bool WZN>
__device__ __forceinline__ void pass1_accum(
    const float* __restrict__ W, const float* __restrict__ z,
    const float* __restrict__ noise, size_t wyo, size_t zoff,
    const int* kidx, int lane, float* s_g)
{
    float acc[CNT];
    #pragma unroll
    for (int t = 0; t < CNT; ++t) acc[t] = 0.0f;

    #pragma unroll 1   // CRITICAL: unrolling multiplies a4/addr live ranges ->
    for (int it = 0; it < 8; ++it) {   // scratch demotion (round-4 lesson)
        const int p = lane + (it << 6);
        const float4 wy4 = ((const float4*)(W + wyo))[p];
        float4 a4[NROW];
        #pragma unroll
        for (int k = 0; k < NROW; ++k) {
            const float4 wk4 = ((const float4*)(W + (size_t)kidx[k] * DD))[p];
            a4[k].x = wy4.x - wk4.x; a4[k].y = wy4.y - wk4.y;
            a4[k].z = wy4.z - wk4.z; a4[k].w = wy4.w - wk4.w;
        }
        float4 z4 = make_float4(0.f, 0.f, 0.f, 0.f), n4 = z4;
        if (WZN) {
            z4 = ((const float4*)(z + zoff))[p];
            n4 = ((const float4*)(noise + zoff))[p];
        }
        #pragma unroll
        for (int e = 0; e < 4; ++e) {
            float ak[NROW];
            #pragma unroll
            for (int k = 0; k < NROW; ++k)
                ak[k] = (e == 0) ? a4[k].x : (e == 1) ? a4[k].y
                      : (e == 2) ? a4[k].z : a4[k].w;
            const float ze = (e == 0) ? z4.x : (e == 1) ? z4.y : (e == 2) ? z4.z : z4.w;
            const float ne = (e == 0) ? n4.x : (e == 1) ? n4.y : (e == 2) ? n4.z : n4.w;
            #pragma unroll
            for (int t = 0; t < CNT; ++t) {
                const int g = LO + t;                 // compile-time constant
                if (g < 55)      acc[t] += ak[PJ[g < 55 ? g : 0]] * ak[PK[g < 55 ? g : 0]];
                else if (g < 65) acc[t] += ak[(g - 55) < NROW ? (g - 55) : 0] * ze;
                else             acc[t] += ak[(g - 65) < NROW ? (g - 65) : 0] * ne;
            }
        }
    }
    // wave covered all of D -> shuffle reduce is the FULL sum
    #pragma unroll
    for (int t = 0; t < CNT; ++t) {
        float x = acc[t];
        #pragma unroll
        for (int off = 32; off > 0; off >>= 1) x += __shfl_down(x, off, 64);
        if (lane == 0) s_g[LO + t] = x;
    }
}

// ---------------- Fused kernel: topk(b) -> aug(b), zero cross-block deps -----
// Rationale: topk is HBM-stream-bound (164 MB logits), aug pass-1 is
// L3-gather-bound (~360 MB row fetches at the measured ~2.8 TB/s path
// ceiling). Scheduler-skewed blocks drive both memory paths concurrently
// instead of serially (150 + ~90 us). Phase registers are disjoint:
// lg[10] (topk) dies before kidx/acc/a4 (aug) — both phases proven <=64
// VGPR standalone; launch_bounds(256,4) caps at 128.
__global__ __launch_bounds__(NT, 4) void fused_kernel(
    const float* __restrict__ logits, const int* __restrict__ y,
    const float* __restrict__ z, const float* __restrict__ W,
    const float* __restrict__ noise, float* __restrict__ out, int write_tail)
{
    __shared__ float s_cv[NW * KK];
    __shared__ int   s_ci[NW * KK];
    __shared__ int   s_kidx[KK];
    __shared__ float s_g[80];          // 75 used: Gram(55), m(10), v(10)
    __shared__ float s_sol[16];        // cvec[10], scale, valid

    const int b = blockIdx.x, tid = threadIdx.x;
    const int lane = tid & 63, wave = tid >> 6;
    const int yb = y[b];

    // ---------------- Phase A: top-10 (round-0 code, known-good) -------------
    {
        float4 lg[10];
        const float4* lrow = (const float4*)(logits + (size_t)b * CC);
        #pragma unroll
        for (int j = 0; j < 10; ++j) {
            const int i4 = tid + 256 * j;
            if (i4 < NF4) lg[j] = lrow[i4];
            else          lg[j] = make_float4(-3e38f, -3e38f, -3e38f, -3e38f);
        }
        #pragma unroll
        for (int j = 0; j < 10; ++j) {        // mask true class
            const int rel = yb - 4 * (tid + 256 * j);
            if (rel == 0) lg[j].x = -3e38f;
            else if (rel == 1) lg[j].y = -3e38f;
            else if (rel == 2) lg[j].z = -3e38f;
            else if (rel == 3) lg[j].w = -3e38f;
        }

        float lbest; int lbidx;
        auto rescan = [&]() {
            lbest = -3.1e38f; lbidx = 0x7fffffff;
            #pragma unroll
            for (int j = 0; j < 10; ++j) {
                const int base = 4 * (tid + 256 * j);
                if (lg[j].x > lbest) { lbest = lg[j].x; lbidx = base + 0; }
                if (lg[j].y > lbest) { lbest = lg[j].y; lbidx = base + 1; }
                if (lg[j].z > lbest) { lbest = lg[j].z; lbidx = base + 2; }
                if (lg[j].w > lbest) { lbest = lg[j].w; lbidx = base + 3; }
            }
        };
        rescan();

        for (int r = 0; r < KK; ++r) {        // 10 wave-local rounds, no barriers
            float bv = lbest; int bi = lbidx;
            #pragma unroll
            for (int off = 32; off > 0; off >>= 1) {
                const float ov = __shfl_down(bv, off, 64);
                const int   oi = __shfl_down(bi, off, 64);
                if (ov > bv || (ov == bv && oi < bi)) { bv = ov; bi = oi; }
            }
            bv = __shfl(bv, 0, 64);
            bi = __shfl(bi, 0, 64);
            if (lane == 0) { s_cv[wave * KK + r] = bv; s_ci[wave * KK + r] = bi; }
            if (lbidx == bi) {                 // owner invalidates and rescans
                const int jw = ((bi >> 2) - tid) >> 8;
                const int cw = bi & 3;
                #pragma unroll
                for (int j = 0; j < 10; ++j) if (j == jw) {
                    if (cw == 0) lg[j].x = -3e38f;
                    else if (cw == 1) lg[j].y = -3e38f;
                    else if (cw == 2) lg[j].z = -3e38f;
                    else lg[j].w = -3e38f;
                }
                rescan();
            }
        }
    }
    __syncthreads();

    if (wave == 0) {                       // top-10 of the 40 wave candidates
        float cv = (lane < NW * KK) ? s_cv[lane] : -3.1e38f;
        int   ci = (lane < NW * KK) ? s_ci[lane] : 0x7fffffff;
        for (int r = 0; r < KK; ++r) {
            float bv = cv; int bi = ci;
            #pragma unroll
            for (int off = 32; off > 0; off >>= 1) {
                const float ov = __shfl_down(bv, off, 64);
                const int   oi = __shfl_down(bi, off, 64);
                if (ov > bv || (ov == bv && oi < bi)) { bv = ov; bi = oi; }
            }
            bi = __shfl(bi, 0, 64);
            if (lane == 0) s_kidx[r] = bi;
            if (ci == bi) cv = -3.1e38f;
        }
    }
    __syncthreads();

    // ---------------- Phase B: Gram/Cholesky augmentation (round-2 code) -----
    int kidx[KK];
    #pragma unroll
    for (int k = 0; k < KK; ++k) kidx[k] = s_kidx[k];

    const size_t zoff = (size_t)b * DD;
    const size_t wyo  = (size_t)yb * DD;

    if (wave == 0)      pass1_accum< 0, 19,  6, false>(W, z, noise, wyo, zoff, kidx, lane, s_g);
    else if (wave == 1) pass1_accum<19, 19,  9, false>(W, z, noise, wyo, zoff, kidx, lane, s_g);
    else if (wave == 2) pass1_accum<38, 17, 10, false>(W, z, noise, wyo, zoff, kidx, lane, s_g);
    else                pass1_accum<55, 20, 10, true >(W, z, noise, wyo, zoff, kidx, lane, s_g);
    __syncthreads();

    if (wave == 0) {   // Cholesky + triangular solves, redundant across wave 0
        float g[75];
        #pragma unroll
        for (int t = 0; t < 75; ++t) g[t] = s_g[t];

        float dinv[KK];
        unsigned keepmask = 0u;
        #pragma unroll
        for (int k = 0; k < KK; ++k) {
            float s = g[TRI(k) + k];
            #pragma unroll
            for (int j = 0; j < KK; ++j) if (j < k) { const float l = g[TRI(k) + j]; s -= l * l; }
            const float dkk = sqrtf(fmaxf(s, 0.0f));
            const bool kp = dkk > 1e-6f;
            if (kp) keepmask |= (1u << k);
            dinv[k] = kp ? 1.0f / dkk : 0.0f;
            g[TRI(k) + k] = dkk;
            #pragma unroll
            for (int i = 0; i < KK; ++i) if (i > k) {
                float t2 = g[TRI(i) + k];
                #pragma unroll
                for (int j = 0; j < KK; ++j) if (j < k) t2 -= g[TRI(i) + j] * g[TRI(k) + j];
                g[TRI(i) + k] = t2 * dinv[k];
            }
        }
        float cvec[KK];
        #pragma unroll
        for (int i = 0; i < KK; ++i) {
            float s = g[65 + i];
            #pragma unroll
            for (int j = 0; j < KK; ++j) if (j < i) s -= g[TRI(i) + j] * cvec[j];
            cvec[i] = s * dinv[i];
        }
        #pragma unroll
        for (int i = KK - 1; i >= 0; --i) {
            float s = cvec[i];
            #pragma unroll
            for (int j = 0; j < KK; ++j) if (j > i) s -= g[TRI(j) + i] * cvec[j];
            cvec[i] = s * dinv[i];
        }
        const float denomf = 6.9914645e-8f;   // 2*EPS*log(20) + EPS (fp32)
        float amin = 3.0e38f;
        #pragma unroll
        for (int k = 0; k < KK; ++k) {
            const float sl = fmaxf(g[55 + k], 0.0f);   // GAMMA = 0
            amin = fminf(amin, sl * sl / denomf);
        }
        const bool valid = (keepmask != 0u) && (amin > 0.0f) && isfinite(amin);
        const float scale = valid ? sqrtf(amin) : 0.0f;
        if (lane == 0) {
            #pragma unroll
            for (int k = 0; k < KK; ++k) s_sol[k] = cvec[k];
            s_sol[10] = scale;
            s_sol[11] = valid ? 1.0f : 0.0f;
        }
    }
    __syncthreads();

    float cvec[KK];
    #pragma unroll
    for (int k = 0; k < KK; ++k) cvec[k] = s_sol[k];
    const float scale = s_sol[10];

    // pass 2: re-gather W chunks (L2-hot: same block just touched them),
    // project, write out
    #pragma unroll
    for (int c = 0; c < 2; ++c) {
        const size_t coff = (size_t)c * 1024;
        const float4 wy4 = ((const float4*)(W + wyo + coff))[tid];
        float4 proj = make_float4(0.f, 0.f, 0.f, 0.f);
        float csum = 0.f;
        #pragma unroll
        for (int k = 0; k < KK; ++k) {
            const float4 wk4 = ((const float4*)(W + (size_t)kidx[k] * DD + coff))[tid];
            proj.x -= cvec[k] * wk4.x; proj.y -= cvec[k] * wk4.y;
            proj.z -= cvec[k] * wk4.z; proj.w -= cvec[k] * wk4.w;
            csum += cvec[k];
        }
        proj.x += csum * wy4.x; proj.y += csum * wy4.y;
        proj.z += csum * wy4.z; proj.w += csum * wy4.w;
        const float4 zc = ((const float4*)(z + zoff + coff))[tid];
        const float4 nc = ((const float4*)(noise + zoff + coff))[tid];
        float4 o;
        o.x = zc.x + scale * (nc.x - proj.x);
        o.y = zc.y + scale * (nc.y - proj.y);
        o.z = zc.z + scale * (nc.z - proj.z);
        o.w = zc.w + scale * (nc.w - proj.w);
        ((float4*)(out + zoff + coff))[tid] = o;
    }

    if (write_tail && tid == 0) {
        out[(size_t)BB * DD + b] = (float)yb;
        out[(size_t)BB * DD + BB + b] = s_sol[11];
    }
}

extern "C" void kernel_launch(void* const* d_in, const int* in_sizes, int n_in,
                              void* d_out, int out_size, void* d_ws, size_t ws_size,
                              hipStream_t stream) {
    const float* z      = (const float*)d_in[0];
    const int*   y      = (const int*)d_in[1];
    const float* logits = (const float*)d_in[2];
    const float* W      = (const float*)d_in[3];
    const float* noise  = (const float*)d_in[4];
    float* out = (float*)d_out;
    const int write_tail = (out_size >= BB * DD + 2 * BB) ? 1 : 0;

    fused_kernel<<<BB, NT, 0, stream>>>(logits, y, z, W, noise, out, write_tail);
}